// Round 3
// baseline (789.853 us; speedup 1.0000x reference)
//
#include <hip/hip_runtime.h>
#include <cmath>

#define N_NODES 100000
#define N_EDGES 1600000
#define IN_DIM 128
#define HID 96
#define NCLS 16
#define NB_SCAN 391   // ceil(N_NODES/256)
#define NPART 8
#define PART_SZ (N_NODES / NPART)  // 12500

// ---------------------------------------------------------------------------
// Register-blocked GEMM: out[r][0..95] = X[r][:] @ W + b, grid-stride.
// Each thread: 1 row x 16 cols (6 col-groups). W staged in LDS.
// STATS: accumulate per-column sum/sumsq (for BatchNorm) via LDS + atomics.
// ---------------------------------------------------------------------------
template <int K, bool STATS>
__global__ __launch_bounds__(256) void gemm_rb(const float* __restrict__ X,
                                               const float* __restrict__ W,
                                               const float* __restrict__ bias,
                                               float* __restrict__ out,
                                               float* __restrict__ sums,
                                               float* __restrict__ sumsq) {
    __shared__ float Ws[K * HID];
    __shared__ float s_sum[HID], s_sq[HID];
    for (int i = threadIdx.x; i < K * HID / 4; i += 256)
        ((float4*)Ws)[i] = ((const float4*)W)[i];
    if (STATS && threadIdx.x < HID) {
        s_sum[threadIdx.x] = 0.f;
        s_sq[threadIdx.x] = 0.f;
    }
    __syncthreads();

    const int total = N_NODES * 6;
    for (int idx = blockIdx.x * 256 + threadIdx.x; idx < total;
         idx += gridDim.x * 256) {
        int r = idx / 6, g = idx % 6;
        const float* xr = X + (size_t)r * K;
        const float* wcol = Ws + g * 16;
        float acc[16];
#pragma unroll
        for (int j = 0; j < 16; ++j) acc[j] = bias[g * 16 + j];

        for (int k = 0; k < K; k += 4) {
            float4 xv = *(const float4*)(xr + k);
#pragma unroll
            for (int kk = 0; kk < 4; ++kk) {
                float x = kk == 0 ? xv.x : kk == 1 ? xv.y : kk == 2 ? xv.z : xv.w;
                const float* wrow = wcol + (k + kk) * HID;
#pragma unroll
                for (int j = 0; j < 16; j += 4) {
                    float4 w = *(const float4*)(wrow + j);
                    acc[j + 0] = fmaf(x, w.x, acc[j + 0]);
                    acc[j + 1] = fmaf(x, w.y, acc[j + 1]);
                    acc[j + 2] = fmaf(x, w.z, acc[j + 2]);
                    acc[j + 3] = fmaf(x, w.w, acc[j + 3]);
                }
            }
        }
        float4* orow = (float4*)(out + (size_t)r * HID + g * 16);
#pragma unroll
        for (int j = 0; j < 16; j += 4)
            orow[j / 4] = make_float4(acc[j], acc[j + 1], acc[j + 2], acc[j + 3]);
        if (STATS) {
#pragma unroll
            for (int j = 0; j < 16; ++j) {
                atomicAdd(&s_sum[g * 16 + j], acc[j]);
                atomicAdd(&s_sq[g * 16 + j], acc[j] * acc[j]);
            }
        }
    }
    if (STATS) {
        __syncthreads();
        if (threadIdx.x < HID) {
            unsafeAtomicAdd(&sums[threadIdx.x], s_sum[threadIdx.x]);
            unsafeAtomicAdd(&sumsq[threadIdx.x], s_sq[threadIdx.x]);
        }
    }
}

// ---------------------------------------------------------------------------
// CSR build, XCD-partitioned: partition p = blockIdx&7 handles dst range
// [p*PART_SZ, (p+1)*PART_SZ). All partitions scan all edges (reads are
// L2/L3-resident); writes/atomics stay local to one XCD's L2.
// ---------------------------------------------------------------------------
__global__ __launch_bounds__(256) void hist_part(const int4* __restrict__ dst4,
                                                 int* __restrict__ deg) {
    int pid = blockIdx.x & (NPART - 1);
    int slot = blockIdx.x >> 3, nslot = gridDim.x >> 3;
    int lo = pid * PART_SZ, hi = lo + PART_SZ;
    for (int i = slot * 256 + threadIdx.x; i < N_EDGES / 4; i += nslot * 256) {
        int4 d = dst4[i];
        if (d.x >= lo && d.x < hi) atomicAdd(&deg[d.x], 1);
        if (d.y >= lo && d.y < hi) atomicAdd(&deg[d.y], 1);
        if (d.z >= lo && d.z < hi) atomicAdd(&deg[d.z], 1);
        if (d.w >= lo && d.w < hi) atomicAdd(&deg[d.w], 1);
    }
}

__global__ __launch_bounds__(256) void scatter_part(const int4* __restrict__ src4,
                                                    const int4* __restrict__ dst4,
                                                    int* __restrict__ cursor,
                                                    int* __restrict__ cols) {
    int pid = blockIdx.x & (NPART - 1);
    int slot = blockIdx.x >> 3, nslot = gridDim.x >> 3;
    int lo = pid * PART_SZ, hi = lo + PART_SZ;
    for (int i = slot * 256 + threadIdx.x; i < N_EDGES / 4; i += nslot * 256) {
        int4 d = dst4[i];
        int4 s = src4[i];
        if (d.x >= lo && d.x < hi) cols[atomicAdd(&cursor[d.x], 1)] = s.x;
        if (d.y >= lo && d.y < hi) cols[atomicAdd(&cursor[d.y], 1)] = s.y;
        if (d.z >= lo && d.z < hi) cols[atomicAdd(&cursor[d.z], 1)] = s.z;
        if (d.w >= lo && d.w < hi) cols[atomicAdd(&cursor[d.w], 1)] = s.w;
    }
}

// ---------------------------------------------------------------------------
// Scan (2-level) over deg -> rp, cursor
// ---------------------------------------------------------------------------
__global__ void scan_blocksum(const int* __restrict__ deg, int* __restrict__ bsums) {
    __shared__ int sm[256];
    int t = threadIdx.x;
    int i = blockIdx.x * 256 + t;
    sm[t] = (i < N_NODES) ? deg[i] : 0;
    __syncthreads();
    for (int s = 128; s > 0; s >>= 1) {
        if (t < s) sm[t] += sm[t + s];
        __syncthreads();
    }
    if (t == 0) bsums[blockIdx.x] = sm[0];
}

__global__ void scan_offsets(const int* __restrict__ bsums, int* __restrict__ boffs) {
    __shared__ int tmp[512];
    int t = threadIdx.x;
    int v = (t < NB_SCAN) ? bsums[t] : 0;
    tmp[t] = v;
    __syncthreads();
    for (int off = 1; off < 512; off <<= 1) {
        int a = (t >= off) ? tmp[t - off] : 0;
        __syncthreads();
        tmp[t] += a;
        __syncthreads();
    }
    if (t < NB_SCAN) boffs[t] = tmp[t] - v;  // exclusive
}

__global__ void scan_final(const int* __restrict__ deg, const int* __restrict__ boffs,
                           int* __restrict__ rp, int* __restrict__ cursor) {
    __shared__ int tmp[256];
    int t = threadIdx.x;
    int i = blockIdx.x * 256 + t;
    int val = (i < N_NODES) ? deg[i] : 0;
    tmp[t] = val;
    __syncthreads();
    for (int off = 1; off < 256; off <<= 1) {
        int a = (t >= off) ? tmp[t - off] : 0;
        __syncthreads();
        tmp[t] += a;
        __syncthreads();
    }
    int excl = tmp[t] - val + boffs[blockIdx.x];
    if (i < N_NODES) {
        rp[i] = excl;
        cursor[i] = excl;
        if (i == N_NODES - 1) rp[N_NODES] = excl + val;
    }
}

// ---------------------------------------------------------------------------
// Gather aggregation: out[v] = f(H[v]) + sum_{u in in(v)} f(H[u]),
// f = identity or relu(x*scale+shift). 24 threads/node, float4 each.
// ---------------------------------------------------------------------------
__device__ __forceinline__ float4 bn_relu4(float4 x, float4 sc, float4 sh) {
    float4 r;
    r.x = fmaxf(fmaf(x.x, sc.x, sh.x), 0.f);
    r.y = fmaxf(fmaf(x.y, sc.y, sh.y), 0.f);
    r.z = fmaxf(fmaf(x.z, sc.z, sh.z), 0.f);
    r.w = fmaxf(fmaf(x.w, sc.w, sh.w), 0.f);
    return r;
}
__device__ __forceinline__ void acc4(float4& a, float4 x) {
    a.x += x.x; a.y += x.y; a.z += x.z; a.w += x.w;
}

template <bool BN>
__global__ __launch_bounds__(192) void gather_kernel(const float* __restrict__ H,
                                                     const int* __restrict__ rp,
                                                     const int* __restrict__ cols,
                                                     const float* __restrict__ scale,
                                                     const float* __restrict__ shift,
                                                     float* __restrict__ out) {
    int idx = blockIdx.x * 192 + threadIdx.x;
    int v = idx / 24, q = idx % 24;
    if (v >= N_NODES) return;

    float4 sc, sh;
    if (BN) {
        sc = ((const float4*)scale)[q];
        sh = ((const float4*)shift)[q];
    }
    const float4* Hq = (const float4*)H;  // row stride = 24 float4

    float4 self = Hq[(size_t)v * 24 + q];
    float4 acc = BN ? bn_relu4(self, sc, sh) : self;

    int beg = rp[v], end = rp[v + 1];
    int j = beg;
    for (; j + 3 < end; j += 4) {
        int u0 = cols[j], u1 = cols[j + 1], u2 = cols[j + 2], u3 = cols[j + 3];
        float4 x0 = Hq[(size_t)u0 * 24 + q];
        float4 x1 = Hq[(size_t)u1 * 24 + q];
        float4 x2 = Hq[(size_t)u2 * 24 + q];
        float4 x3 = Hq[(size_t)u3 * 24 + q];
        acc4(acc, BN ? bn_relu4(x0, sc, sh) : x0);
        acc4(acc, BN ? bn_relu4(x1, sc, sh) : x1);
        acc4(acc, BN ? bn_relu4(x2, sc, sh) : x2);
        acc4(acc, BN ? bn_relu4(x3, sc, sh) : x3);
    }
    for (; j < end; ++j) {
        int u = cols[j];
        float4 x = Hq[(size_t)u * 24 + q];
        acc4(acc, BN ? bn_relu4(x, sc, sh) : x);
    }
    ((float4*)out)[(size_t)v * 24 + q] = acc;
}

// ---------------------------------------------------------------------------
__global__ void bn_finalize(const float* __restrict__ sums, const float* __restrict__ sumsq,
                            const float* __restrict__ g, const float* __restrict__ be,
                            float* __restrict__ scale, float* __restrict__ shift) {
    int c = threadIdx.x;
    if (c < HID) {
        float mu = sums[c] * (1.0f / N_NODES);
        float var = sumsq[c] * (1.0f / N_NODES) - mu * mu;
        float rstd = rsqrtf(var + 1e-5f);
        float s = g[c] * rstd;
        scale[c] = s;
        shift[c] = be[c] - mu * s;
    }
}

// ---------------------------------------------------------------------------
// Readout: stage 16 BN+ReLU'd rows in LDS (coalesced), 16 lanes per row
// (one class each), shuffle-reduce log_softmax, coalesced store.
// ---------------------------------------------------------------------------
__global__ __launch_bounds__(256) void readout_kernel(const float* __restrict__ X,
                                                      const float* __restrict__ scale,
                                                      const float* __restrict__ shift,
                                                      const float* __restrict__ Wr,
                                                      const float* __restrict__ br,
                                                      float* __restrict__ out) {
    __shared__ float Ws[HID * NCLS];      // 6 KB
    __shared__ float XL[16 * 97];         // padded stride 97 vs bank conflicts
    __shared__ float scs[HID], shs[HID], bs[NCLS];
    for (int i = threadIdx.x; i < HID * NCLS / 4; i += 256)
        ((float4*)Ws)[i] = ((const float4*)Wr)[i];
    if (threadIdx.x < HID) {
        scs[threadIdx.x] = scale[threadIdx.x];
        shs[threadIdx.x] = shift[threadIdx.x];
    }
    if (threadIdx.x < NCLS) bs[threadIdx.x] = br[threadIdx.x];

    int rr = threadIdx.x >> 4, t = threadIdx.x & 15;
    for (int tile = blockIdx.x; tile < N_NODES / 16; tile += gridDim.x) {
        int rbase = tile * 16;
        __syncthreads();  // XL free (also covers initial Ws/scs staging)
        for (int i = threadIdx.x; i < 16 * HID; i += 256) {
            int row = i / HID, col = i - row * HID;
            float z = fmaf(X[(size_t)rbase * HID + i], scs[col], shs[col]);
            XL[row * 97 + col] = fmaxf(z, 0.f);
        }
        __syncthreads();
        float acc = bs[t];
        const float* xrow = &XL[rr * 97];
#pragma unroll 4
        for (int k = 0; k < HID; ++k) acc = fmaf(xrow[k], Ws[k * NCLS + t], acc);
        float m = acc;
#pragma unroll
        for (int off = 8; off; off >>= 1) m = fmaxf(m, __shfl_xor(m, off, 16));
        float e = expf(acc - m);
        float s = e;
#pragma unroll
        for (int off = 8; off; off >>= 1) s += __shfl_xor(s, off, 16);
        float lse = m + logf(s);
        out[(size_t)rbase * NCLS + threadIdx.x] = acc - lse;
    }
}

// ---------------------------------------------------------------------------
extern "C" void kernel_launch(void* const* d_in, const int* in_sizes, int n_in,
                              void* d_out, int out_size, void* d_ws, size_t ws_size,
                              hipStream_t stream) {
    const float* h     = (const float*)d_in[0];
    const int*   src   = (const int*)d_in[1];
    const int*   dst   = (const int*)d_in[2];
    const float* W_emb = (const float*)d_in[3];
    const float* b_emb = (const float*)d_in[4];
    const float* W1    = (const float*)d_in[5];
    const float* b1    = (const float*)d_in[6];
    const float* g1    = (const float*)d_in[7];
    const float* be1   = (const float*)d_in[8];
    const float* W2    = (const float*)d_in[9];
    const float* b2    = (const float*)d_in[10];
    const float* g2    = (const float*)d_in[11];
    const float* be2   = (const float*)d_in[12];
    const float* Wr    = (const float*)d_in[13];
    const float* br    = (const float*)d_in[14];

    const size_t nh = (size_t)N_NODES * HID;
    float* P0 = (float*)d_ws;          // 38.4 MB
    float* P1 = P0 + nh;               // 38.4 MB
    int* deg    = (int*)(P1 + nh);     // N
    int* rp     = deg + N_NODES;       // N+1
    int* cursor = rp + N_NODES + 1;    // N
    int* cols   = cursor + N_NODES;    // E
    int* bsums  = cols + N_EDGES;      // NB_SCAN
    int* boffs  = bsums + 512;         // NB_SCAN
    float* sums  = (float*)(boffs + 512);  // 96
    float* sumsq = sums + 96;              // 96
    float* scale = sumsq + 96;             // 96
    float* shift = scale + 96;             // 96

    const int blkA = (N_NODES * 24 + 191) / 192;     // 12500
    const int blkPart = 1024;                        // 8 partitions x 128 slots
    const int blkGemm = 1024;

    // --- CSR build (XCD-partitioned) ---
    hipMemsetAsync(deg, 0, N_NODES * sizeof(int), stream);
    hist_part<<<blkPart, 256, 0, stream>>>((const int4*)dst, deg);
    scan_blocksum<<<NB_SCAN, 256, 0, stream>>>(deg, bsums);
    scan_offsets<<<1, 512, 0, stream>>>(bsums, boffs);
    scan_final<<<NB_SCAN, 256, 0, stream>>>(deg, boffs, rp, cursor);
    scatter_part<<<blkPart, 256, 0, stream>>>((const int4*)src, (const int4*)dst,
                                              cursor, cols);

    // --- embedding: P0 = h @ W_emb + b_emb ---
    hipLaunchKernelGGL((gemm_rb<IN_DIM, false>), dim3(blkGemm), dim3(256), 0, stream,
                       h, W_emb, b_emb, P0, nullptr, nullptr);

    // --- GIN layer 1 ---
    hipLaunchKernelGGL((gather_kernel<false>), dim3(blkA), dim3(192), 0, stream,
                       P0, rp, cols, nullptr, nullptr, P1);
    hipMemsetAsync(sums, 0, 2 * HID * sizeof(float), stream);
    hipLaunchKernelGGL((gemm_rb<HID, true>), dim3(blkGemm), dim3(256), 0, stream,
                       P1, W1, b1, P0, sums, sumsq);         // P0 = C1 + stats
    bn_finalize<<<1, 128, 0, stream>>>(sums, sumsq, g1, be1, scale, shift);

    // --- GIN layer 2 (BN1+ReLU fused into gather) ---
    hipLaunchKernelGGL((gather_kernel<true>), dim3(blkA), dim3(192), 0, stream,
                       P0, rp, cols, scale, shift, P1);
    hipMemsetAsync(sums, 0, 2 * HID * sizeof(float), stream);
    hipLaunchKernelGGL((gemm_rb<HID, true>), dim3(blkGemm), dim3(256), 0, stream,
                       P1, W2, b2, P0, sums, sumsq);         // P0 = C2 + stats
    bn_finalize<<<1, 128, 0, stream>>>(sums, sumsq, g2, be2, scale, shift);

    // --- readout (BN2+ReLU fused) + log_softmax ---
    readout_kernel<<<2048, 256, 0, stream>>>(P0, scale, shift, Wr, br, (float*)d_out);
}

// Round 4
// 618.426 us; speedup vs baseline: 1.2772x; 1.2772x over previous
//
#include <hip/hip_runtime.h>
#include <cmath>

#define N_NODES 100000
#define N_EDGES 1600000
#define IN_DIM 128
#define HID 96
#define NCLS 16
#define NB_SCAN 391   // ceil(N_NODES/256)
#define NPART 8
#define PART_SZ (N_NODES / NPART)  // 12500
#define NB_STATS 300

// ---------------------------------------------------------------------------
// Register-blocked GEMM: out[r][0..95] = X[r][:] @ W + b
// One work-item per thread: 1 row x 16 cols (6 col-groups). W, b in LDS.
// ---------------------------------------------------------------------------
template <int K>
__global__ __launch_bounds__(256) void gemm_rb(const float* __restrict__ X,
                                               const float* __restrict__ W,
                                               const float* __restrict__ bias,
                                               float* __restrict__ out) {
    __shared__ float Ws[K * HID];
    __shared__ float bs[HID];
    for (int i = threadIdx.x; i < K * HID / 4; i += 256)
        ((float4*)Ws)[i] = ((const float4*)W)[i];
    if (threadIdx.x < HID) bs[threadIdx.x] = bias[threadIdx.x];
    __syncthreads();

    int idx = blockIdx.x * 256 + threadIdx.x;
    int r = idx / 6, g = idx % 6;
    if (r >= N_NODES) return;

    const float* xr = X + (size_t)r * K;
    const float* wcol = Ws + g * 16;
    float acc[16];
#pragma unroll
    for (int j = 0; j < 16; ++j) acc[j] = bs[g * 16 + j];

    for (int k = 0; k < K; k += 4) {
        float4 xv = *(const float4*)(xr + k);
#pragma unroll
        for (int kk = 0; kk < 4; ++kk) {
            float x = kk == 0 ? xv.x : kk == 1 ? xv.y : kk == 2 ? xv.z : xv.w;
            const float* wrow = wcol + (k + kk) * HID;
#pragma unroll
            for (int j = 0; j < 16; j += 4) {
                float4 w = *(const float4*)(wrow + j);
                acc[j + 0] = fmaf(x, w.x, acc[j + 0]);
                acc[j + 1] = fmaf(x, w.y, acc[j + 1]);
                acc[j + 2] = fmaf(x, w.z, acc[j + 2]);
                acc[j + 3] = fmaf(x, w.w, acc[j + 3]);
            }
        }
    }
    float4* orow = (float4*)(out + (size_t)r * HID + g * 16);
#pragma unroll
    for (int j = 0; j < 16; j += 4)
        orow[j / 4] = make_float4(acc[j], acc[j + 1], acc[j + 2], acc[j + 3]);
}

// ---------------------------------------------------------------------------
// CSR build, XCD-partitioned (partition = blockIdx&7 → matches round-robin
// block->XCD dispatch; writes/atomics stay in one XCD's L2).
// ---------------------------------------------------------------------------
__global__ __launch_bounds__(256) void hist_part(const int4* __restrict__ dst4,
                                                 int* __restrict__ deg) {
    int pid = blockIdx.x & (NPART - 1);
    int slot = blockIdx.x >> 3, nslot = gridDim.x >> 3;
    int lo = pid * PART_SZ, hi = lo + PART_SZ;
    for (int i = slot * 256 + threadIdx.x; i < N_EDGES / 4; i += nslot * 256) {
        int4 d = dst4[i];
        if (d.x >= lo && d.x < hi) atomicAdd(&deg[d.x], 1);
        if (d.y >= lo && d.y < hi) atomicAdd(&deg[d.y], 1);
        if (d.z >= lo && d.z < hi) atomicAdd(&deg[d.z], 1);
        if (d.w >= lo && d.w < hi) atomicAdd(&deg[d.w], 1);
    }
}

__global__ __launch_bounds__(256) void scatter_part(const int4* __restrict__ src4,
                                                    const int4* __restrict__ dst4,
                                                    int* __restrict__ cursor,
                                                    int* __restrict__ cols) {
    int pid = blockIdx.x & (NPART - 1);
    int slot = blockIdx.x >> 3, nslot = gridDim.x >> 3;
    int lo = pid * PART_SZ, hi = lo + PART_SZ;
    for (int i = slot * 256 + threadIdx.x; i < N_EDGES / 4; i += nslot * 256) {
        int4 d = dst4[i];
        int4 s = src4[i];
        if (d.x >= lo && d.x < hi) cols[atomicAdd(&cursor[d.x], 1)] = s.x;
        if (d.y >= lo && d.y < hi) cols[atomicAdd(&cursor[d.y], 1)] = s.y;
        if (d.z >= lo && d.z < hi) cols[atomicAdd(&cursor[d.z], 1)] = s.z;
        if (d.w >= lo && d.w < hi) cols[atomicAdd(&cursor[d.w], 1)] = s.w;
    }
}

// ---------------------------------------------------------------------------
// Scan (2-level) over deg -> rp, cursor
// ---------------------------------------------------------------------------
__global__ void scan_blocksum(const int* __restrict__ deg, int* __restrict__ bsums) {
    __shared__ int sm[256];
    int t = threadIdx.x;
    int i = blockIdx.x * 256 + t;
    sm[t] = (i < N_NODES) ? deg[i] : 0;
    __syncthreads();
    for (int s = 128; s > 0; s >>= 1) {
        if (t < s) sm[t] += sm[t + s];
        __syncthreads();
    }
    if (t == 0) bsums[blockIdx.x] = sm[0];
}

__global__ void scan_offsets(const int* __restrict__ bsums, int* __restrict__ boffs) {
    __shared__ int tmp[512];
    int t = threadIdx.x;
    int v = (t < NB_SCAN) ? bsums[t] : 0;
    tmp[t] = v;
    __syncthreads();
    for (int off = 1; off < 512; off <<= 1) {
        int a = (t >= off) ? tmp[t - off] : 0;
        __syncthreads();
        tmp[t] += a;
        __syncthreads();
    }
    if (t < NB_SCAN) boffs[t] = tmp[t] - v;  // exclusive
}

__global__ void scan_final(const int* __restrict__ deg, const int* __restrict__ boffs,
                           int* __restrict__ rp, int* __restrict__ cursor) {
    __shared__ int tmp[256];
    int t = threadIdx.x;
    int i = blockIdx.x * 256 + t;
    int val = (i < N_NODES) ? deg[i] : 0;
    tmp[t] = val;
    __syncthreads();
    for (int off = 1; off < 256; off <<= 1) {
        int a = (t >= off) ? tmp[t - off] : 0;
        __syncthreads();
        tmp[t] += a;
        __syncthreads();
    }
    int excl = tmp[t] - val + boffs[blockIdx.x];
    if (i < N_NODES) {
        rp[i] = excl;
        cursor[i] = excl;
        if (i == N_NODES - 1) rp[N_NODES] = excl + val;
    }
}

// ---------------------------------------------------------------------------
// Gather aggregation: out[v] = f(H[v]) + sum_{u in in(v)} f(H[u]),
// f = identity or relu(x*scale+shift). 24 threads/node, float4 each.
// ---------------------------------------------------------------------------
__device__ __forceinline__ float4 bn_relu4(float4 x, float4 sc, float4 sh) {
    float4 r;
    r.x = fmaxf(fmaf(x.x, sc.x, sh.x), 0.f);
    r.y = fmaxf(fmaf(x.y, sc.y, sh.y), 0.f);
    r.z = fmaxf(fmaf(x.z, sc.z, sh.z), 0.f);
    r.w = fmaxf(fmaf(x.w, sc.w, sh.w), 0.f);
    return r;
}
__device__ __forceinline__ void acc4(float4& a, float4 x) {
    a.x += x.x; a.y += x.y; a.z += x.z; a.w += x.w;
}

template <bool BN>
__global__ __launch_bounds__(192) void gather_kernel(const float* __restrict__ H,
                                                     const int* __restrict__ rp,
                                                     const int* __restrict__ cols,
                                                     const float* __restrict__ scale,
                                                     const float* __restrict__ shift,
                                                     float* __restrict__ out) {
    int idx = blockIdx.x * 192 + threadIdx.x;
    int v = idx / 24, q = idx % 24;
    if (v >= N_NODES) return;

    float4 sc, sh;
    if (BN) {
        sc = ((const float4*)scale)[q];
        sh = ((const float4*)shift)[q];
    }
    const float4* Hq = (const float4*)H;  // row stride = 24 float4

    float4 self = Hq[(size_t)v * 24 + q];
    float4 acc = BN ? bn_relu4(self, sc, sh) : self;

    int beg = rp[v], end = rp[v + 1];
    int j = beg;
    for (; j + 3 < end; j += 4) {
        int u0 = cols[j], u1 = cols[j + 1], u2 = cols[j + 2], u3 = cols[j + 3];
        float4 x0 = Hq[(size_t)u0 * 24 + q];
        float4 x1 = Hq[(size_t)u1 * 24 + q];
        float4 x2 = Hq[(size_t)u2 * 24 + q];
        float4 x3 = Hq[(size_t)u3 * 24 + q];
        acc4(acc, BN ? bn_relu4(x0, sc, sh) : x0);
        acc4(acc, BN ? bn_relu4(x1, sc, sh) : x1);
        acc4(acc, BN ? bn_relu4(x2, sc, sh) : x2);
        acc4(acc, BN ? bn_relu4(x3, sc, sh) : x3);
    }
    for (; j < end; ++j) {
        int u = cols[j];
        float4 x = Hq[(size_t)u * 24 + q];
        acc4(acc, BN ? bn_relu4(x, sc, sh) : x);
    }
    ((float4*)out)[(size_t)v * 24 + q] = acc;
}

// ---------------------------------------------------------------------------
// BN stats, deterministic: float4 per thread, register accumulate over
// grid-stride rows, LDS tree reduce, per-block partials to global.
// 192 threads = 8 row-slots x 24 float4-chunks.
// ---------------------------------------------------------------------------
__global__ __launch_bounds__(192) void bn_stats(const float4* __restrict__ Z4,
                                                float* __restrict__ psums,
                                                float* __restrict__ psq) {
    int q = threadIdx.x % 24, rs = threadIdx.x / 24;
    float4 s = make_float4(0.f, 0.f, 0.f, 0.f);
    float4 sq = make_float4(0.f, 0.f, 0.f, 0.f);
    for (int r = blockIdx.x * 8 + rs; r < N_NODES; r += gridDim.x * 8) {
        float4 v = Z4[(size_t)r * 24 + q];
        s.x += v.x; s.y += v.y; s.z += v.z; s.w += v.w;
        sq.x = fmaf(v.x, v.x, sq.x);
        sq.y = fmaf(v.y, v.y, sq.y);
        sq.z = fmaf(v.z, v.z, sq.z);
        sq.w = fmaf(v.w, v.w, sq.w);
    }
    __shared__ float4 ls[8][24], lq[8][24];
    ls[rs][q] = s;
    lq[rs][q] = sq;
    __syncthreads();
    if (threadIdx.x < 24) {
        float4 S = ls[0][q], Q = lq[0][q];
#pragma unroll
        for (int i = 1; i < 8; ++i) {
            acc4(S, ls[i][q]);
            acc4(Q, lq[i][q]);
        }
        ((float4*)(psums + (size_t)blockIdx.x * HID))[q] = S;
        ((float4*)(psq + (size_t)blockIdx.x * HID))[q] = Q;
    }
}

__global__ void bn_finalize(const float* __restrict__ psums, const float* __restrict__ psq,
                            const float* __restrict__ g, const float* __restrict__ be,
                            float* __restrict__ scale, float* __restrict__ shift) {
    int c = threadIdx.x;
    if (c < HID) {
        float S = 0.f, Q = 0.f;
        for (int b = 0; b < NB_STATS; ++b) {
            S += psums[(size_t)b * HID + c];
            Q += psq[(size_t)b * HID + c];
        }
        float mu = S * (1.0f / N_NODES);
        float var = Q * (1.0f / N_NODES) - mu * mu;
        float rstd = rsqrtf(var + 1e-5f);
        float sc = g[c] * rstd;
        scale[c] = sc;
        shift[c] = be[c] - mu * sc;
    }
}

// ---------------------------------------------------------------------------
// Readout: stage 16 BN+ReLU'd rows in LDS (coalesced), 16 lanes per row
// (one class each), shuffle-reduce log_softmax, coalesced store.
// ---------------------------------------------------------------------------
__global__ __launch_bounds__(256) void readout_kernel(const float* __restrict__ X,
                                                      const float* __restrict__ scale,
                                                      const float* __restrict__ shift,
                                                      const float* __restrict__ Wr,
                                                      const float* __restrict__ br,
                                                      float* __restrict__ out) {
    __shared__ float Ws[HID * NCLS];
    __shared__ float XL[16 * 97];
    __shared__ float scs[HID], shs[HID], bs[NCLS];
    for (int i = threadIdx.x; i < HID * NCLS / 4; i += 256)
        ((float4*)Ws)[i] = ((const float4*)Wr)[i];
    if (threadIdx.x < HID) {
        scs[threadIdx.x] = scale[threadIdx.x];
        shs[threadIdx.x] = shift[threadIdx.x];
    }
    if (threadIdx.x < NCLS) bs[threadIdx.x] = br[threadIdx.x];

    int rr = threadIdx.x >> 4, t = threadIdx.x & 15;
    for (int tile = blockIdx.x; tile < N_NODES / 16; tile += gridDim.x) {
        int rbase = tile * 16;
        __syncthreads();
        for (int i = threadIdx.x; i < 16 * HID; i += 256) {
            int row = i / HID, col = i - row * HID;
            float z = fmaf(X[(size_t)rbase * HID + i], scs[col], shs[col]);
            XL[row * 97 + col] = fmaxf(z, 0.f);
        }
        __syncthreads();
        float acc = bs[t];
        const float* xrow = &XL[rr * 97];
#pragma unroll 4
        for (int k = 0; k < HID; ++k) acc = fmaf(xrow[k], Ws[k * NCLS + t], acc);
        float m = acc;
#pragma unroll
        for (int off = 8; off; off >>= 1) m = fmaxf(m, __shfl_xor(m, off, 16));
        float e = expf(acc - m);
        float s = e;
#pragma unroll
        for (int off = 8; off; off >>= 1) s += __shfl_xor(s, off, 16);
        float lse = m + logf(s);
        out[(size_t)rbase * NCLS + threadIdx.x] = acc - lse;
    }
}

// ---------------------------------------------------------------------------
extern "C" void kernel_launch(void* const* d_in, const int* in_sizes, int n_in,
                              void* d_out, int out_size, void* d_ws, size_t ws_size,
                              hipStream_t stream) {
    const float* h     = (const float*)d_in[0];
    const int*   src   = (const int*)d_in[1];
    const int*   dst   = (const int*)d_in[2];
    const float* W_emb = (const float*)d_in[3];
    const float* b_emb = (const float*)d_in[4];
    const float* W1    = (const float*)d_in[5];
    const float* b1    = (const float*)d_in[6];
    const float* g1    = (const float*)d_in[7];
    const float* be1   = (const float*)d_in[8];
    const float* W2    = (const float*)d_in[9];
    const float* b2    = (const float*)d_in[10];
    const float* g2    = (const float*)d_in[11];
    const float* be2   = (const float*)d_in[12];
    const float* Wr    = (const float*)d_in[13];
    const float* br    = (const float*)d_in[14];

    const size_t nh = (size_t)N_NODES * HID;
    float* P0 = (float*)d_ws;          // 38.4 MB
    float* P1 = P0 + nh;               // 38.4 MB
    int* deg    = (int*)(P1 + nh);     // N
    int* rp     = deg + N_NODES;       // N+1
    int* cursor = rp + N_NODES + 1;    // N
    int* cols   = cursor + N_NODES;    // E
    int* bsums  = cols + N_EDGES;      // NB_SCAN
    int* boffs  = bsums + 512;         // NB_SCAN
    float* psums = (float*)(boffs + 512);   // NB_STATS*96
    float* psq   = psums + NB_STATS * HID;  // NB_STATS*96
    float* scale = psq + NB_STATS * HID;    // 96
    float* shift = scale + HID;             // 96

    const int blkA = (N_NODES * 24 + 191) / 192;     // 12500
    const int blkG = (N_NODES * 6 + 255) / 256;      // 2344
    const int blkPart = 1024;

    // --- CSR build (XCD-partitioned) ---
    hipMemsetAsync(deg, 0, N_NODES * sizeof(int), stream);
    hist_part<<<blkPart, 256, 0, stream>>>((const int4*)dst, deg);
    scan_blocksum<<<NB_SCAN, 256, 0, stream>>>(deg, bsums);
    scan_offsets<<<1, 512, 0, stream>>>(bsums, boffs);
    scan_final<<<NB_SCAN, 256, 0, stream>>>(deg, boffs, rp, cursor);
    scatter_part<<<blkPart, 256, 0, stream>>>((const int4*)src, (const int4*)dst,
                                              cursor, cols);

    // --- embedding: P0 = h @ W_emb + b_emb ---
    hipLaunchKernelGGL((gemm_rb<IN_DIM>), dim3(blkG), dim3(256), 0, stream,
                       h, W_emb, b_emb, P0);

    // --- GIN layer 1 ---
    hipLaunchKernelGGL((gather_kernel<false>), dim3(blkA), dim3(192), 0, stream,
                       P0, rp, cols, nullptr, nullptr, P1);
    hipLaunchKernelGGL((gemm_rb<HID>), dim3(blkG), dim3(256), 0, stream,
                       P1, W1, b1, P0);                      // P0 = C1
    bn_stats<<<NB_STATS, 192, 0, stream>>>((const float4*)P0, psums, psq);
    bn_finalize<<<1, 128, 0, stream>>>(psums, psq, g1, be1, scale, shift);

    // --- GIN layer 2 (BN1+ReLU fused into gather) ---
    hipLaunchKernelGGL((gather_kernel<true>), dim3(blkA), dim3(192), 0, stream,
                       P0, rp, cols, scale, shift, P1);
    hipLaunchKernelGGL((gemm_rb<HID>), dim3(blkG), dim3(256), 0, stream,
                       P1, W2, b2, P0);                      // P0 = C2
    bn_stats<<<NB_STATS, 192, 0, stream>>>((const float4*)P0, psums, psq);
    bn_finalize<<<1, 128, 0, stream>>>(psums, psq, g2, be2, scale, shift);

    // --- readout (BN2+ReLU fused) + log_softmax ---
    readout_kernel<<<2048, 256, 0, stream>>>(P0, scale, shift, Wr, br, (float*)d_out);
}

// Round 5
// 552.975 us; speedup vs baseline: 1.4284x; 1.1184x over previous
//
#include <hip/hip_runtime.h>
#include <cmath>

#define N_NODES 100000
#define N_EDGES 1600000
#define IN_DIM 128
#define HID 96
#define NCLS 16
#define NB_SCAN 391   // ceil(N_NODES/256)
#define NPART 8
#define PART_SZ (N_NODES / NPART)  // 12500
#define NB_STATS 300

// ---------------------------------------------------------------------------
// Tiled GEMM: out[r][0..95] = X[r][:] @ W + b.
// Block = 192 threads = 32 row-clusters x 6 col-groups; thread = 4 rows x 16
// cols (64 accumulators). W staged group-major in LDS with stride K*16+4:
// bank offset per group = 4g (+const) -> 6 groups on distinct bank quads,
// conflict-free ds_read_b128. Rows clamped to N-1 (duplicates benign).
// ---------------------------------------------------------------------------
template <int K>
__global__ __launch_bounds__(192) void gemm_tile(const float* __restrict__ X,
                                                 const float* __restrict__ W,
                                                 const float* __restrict__ bias,
                                                 float* __restrict__ out) {
    constexpr int GSTRIDE = K * 16 + 4;
    __shared__ float Ws[6 * GSTRIDE];
    __shared__ float bs[HID];
    for (int i = threadIdx.x; i < K * HID / 4; i += 192) {
        int flat = i * 4;
        int k = flat / HID, c = flat - k * HID;  // c % 4 == 0
        int g = c / 16, j = c - g * 16;
        *(float4*)&Ws[g * GSTRIDE + k * 16 + j] = ((const float4*)W)[i];
    }
    if (threadIdx.x < HID) bs[threadIdx.x] = bias[threadIdx.x];
    __syncthreads();

    const int g = threadIdx.x % 6;
    const int rc = threadIdx.x / 6;
    const int rbase = blockIdx.x * 128 + rc * 4;
    const int r0 = min(rbase + 0, N_NODES - 1);
    const int r1 = min(rbase + 1, N_NODES - 1);
    const int r2 = min(rbase + 2, N_NODES - 1);
    const int r3 = min(rbase + 3, N_NODES - 1);
    const float* x0 = X + (size_t)r0 * K;
    const float* x1 = X + (size_t)r1 * K;
    const float* x2 = X + (size_t)r2 * K;
    const float* x3 = X + (size_t)r3 * K;
    const float* wg = Ws + g * GSTRIDE;

    float acc[4][16];
#pragma unroll
    for (int j = 0; j < 16; ++j) {
        float bj = bs[g * 16 + j];
        acc[0][j] = bj; acc[1][j] = bj; acc[2][j] = bj; acc[3][j] = bj;
    }

    for (int k = 0; k < K; k += 4) {
        float4 a0 = *(const float4*)(x0 + k);
        float4 a1 = *(const float4*)(x1 + k);
        float4 a2 = *(const float4*)(x2 + k);
        float4 a3 = *(const float4*)(x3 + k);
#pragma unroll
        for (int kk = 0; kk < 4; ++kk) {
            const float* wrow = wg + (k + kk) * 16;
            float4 w0 = *(const float4*)(wrow + 0);
            float4 w1 = *(const float4*)(wrow + 4);
            float4 w2 = *(const float4*)(wrow + 8);
            float4 w3 = *(const float4*)(wrow + 12);
            float xs0 = kk == 0 ? a0.x : kk == 1 ? a0.y : kk == 2 ? a0.z : a0.w;
            float xs1 = kk == 0 ? a1.x : kk == 1 ? a1.y : kk == 2 ? a1.z : a1.w;
            float xs2 = kk == 0 ? a2.x : kk == 1 ? a2.y : kk == 2 ? a2.z : a2.w;
            float xs3 = kk == 0 ? a3.x : kk == 1 ? a3.y : kk == 2 ? a3.z : a3.w;
            const float wv[16] = {w0.x, w0.y, w0.z, w0.w, w1.x, w1.y, w1.z, w1.w,
                                  w2.x, w2.y, w2.z, w2.w, w3.x, w3.y, w3.z, w3.w};
#pragma unroll
            for (int j = 0; j < 16; ++j) {
                acc[0][j] = fmaf(xs0, wv[j], acc[0][j]);
                acc[1][j] = fmaf(xs1, wv[j], acc[1][j]);
                acc[2][j] = fmaf(xs2, wv[j], acc[2][j]);
                acc[3][j] = fmaf(xs3, wv[j], acc[3][j]);
            }
        }
    }
    const int rr[4] = {r0, r1, r2, r3};
#pragma unroll
    for (int i = 0; i < 4; ++i) {
        float4* orow = (float4*)(out + (size_t)rr[i] * HID + g * 16);
#pragma unroll
        for (int j = 0; j < 16; j += 4)
            orow[j / 4] = make_float4(acc[i][j], acc[i][j + 1], acc[i][j + 2], acc[i][j + 3]);
    }
}

// ---------------------------------------------------------------------------
// CSR build, XCD-partitioned (partition = blockIdx&7 -> round-robin XCD;
// writes/atomics stay in one XCD's L2).
// ---------------------------------------------------------------------------
__global__ __launch_bounds__(256) void hist_part(const int4* __restrict__ dst4,
                                                 int* __restrict__ deg) {
    int pid = blockIdx.x & (NPART - 1);
    int slot = blockIdx.x >> 3, nslot = gridDim.x >> 3;
    int lo = pid * PART_SZ, hi = lo + PART_SZ;
    for (int i = slot * 256 + threadIdx.x; i < N_EDGES / 4; i += nslot * 256) {
        int4 d = dst4[i];
        if (d.x >= lo && d.x < hi) atomicAdd(&deg[d.x], 1);
        if (d.y >= lo && d.y < hi) atomicAdd(&deg[d.y], 1);
        if (d.z >= lo && d.z < hi) atomicAdd(&deg[d.z], 1);
        if (d.w >= lo && d.w < hi) atomicAdd(&deg[d.w], 1);
    }
}

__global__ __launch_bounds__(256) void scatter_part(const int4* __restrict__ src4,
                                                    const int4* __restrict__ dst4,
                                                    int* __restrict__ cursor,
                                                    int* __restrict__ cols) {
    int pid = blockIdx.x & (NPART - 1);
    int slot = blockIdx.x >> 3, nslot = gridDim.x >> 3;
    int lo = pid * PART_SZ, hi = lo + PART_SZ;
    for (int i = slot * 256 + threadIdx.x; i < N_EDGES / 4; i += nslot * 256) {
        int4 d = dst4[i];
        int4 s = src4[i];
        if (d.x >= lo && d.x < hi) cols[atomicAdd(&cursor[d.x], 1)] = s.x;
        if (d.y >= lo && d.y < hi) cols[atomicAdd(&cursor[d.y], 1)] = s.y;
        if (d.z >= lo && d.z < hi) cols[atomicAdd(&cursor[d.z], 1)] = s.z;
        if (d.w >= lo && d.w < hi) cols[atomicAdd(&cursor[d.w], 1)] = s.w;
    }
}

// ---------------------------------------------------------------------------
// Scan (2-level) over deg -> rp, cursor
// ---------------------------------------------------------------------------
__global__ void scan_blocksum(const int* __restrict__ deg, int* __restrict__ bsums) {
    __shared__ int sm[256];
    int t = threadIdx.x;
    int i = blockIdx.x * 256 + t;
    sm[t] = (i < N_NODES) ? deg[i] : 0;
    __syncthreads();
    for (int s = 128; s > 0; s >>= 1) {
        if (t < s) sm[t] += sm[t + s];
        __syncthreads();
    }
    if (t == 0) bsums[blockIdx.x] = sm[0];
}

__global__ void scan_offsets(const int* __restrict__ bsums, int* __restrict__ boffs) {
    __shared__ int tmp[512];
    int t = threadIdx.x;
    int v = (t < NB_SCAN) ? bsums[t] : 0;
    tmp[t] = v;
    __syncthreads();
    for (int off = 1; off < 512; off <<= 1) {
        int a = (t >= off) ? tmp[t - off] : 0;
        __syncthreads();
        tmp[t] += a;
        __syncthreads();
    }
    if (t < NB_SCAN) boffs[t] = tmp[t] - v;  // exclusive
}

__global__ void scan_final(const int* __restrict__ deg, const int* __restrict__ boffs,
                           int* __restrict__ rp, int* __restrict__ cursor) {
    __shared__ int tmp[256];
    int t = threadIdx.x;
    int i = blockIdx.x * 256 + t;
    int val = (i < N_NODES) ? deg[i] : 0;
    tmp[t] = val;
    __syncthreads();
    for (int off = 1; off < 256; off <<= 1) {
        int a = (t >= off) ? tmp[t - off] : 0;
        __syncthreads();
        tmp[t] += a;
        __syncthreads();
    }
    int excl = tmp[t] - val + boffs[blockIdx.x];
    if (i < N_NODES) {
        rp[i] = excl;
        cursor[i] = excl;
        if (i == N_NODES - 1) rp[N_NODES] = excl + val;
    }
}

// ---------------------------------------------------------------------------
// Gather aggregation: out[v] = f(H[v]) + sum_{u in in(v)} f(H[u]),
// f = identity or relu(x*scale+shift). 24 threads/node, float4 each.
// ---------------------------------------------------------------------------
__device__ __forceinline__ float4 bn_relu4(float4 x, float4 sc, float4 sh) {
    float4 r;
    r.x = fmaxf(fmaf(x.x, sc.x, sh.x), 0.f);
    r.y = fmaxf(fmaf(x.y, sc.y, sh.y), 0.f);
    r.z = fmaxf(fmaf(x.z, sc.z, sh.z), 0.f);
    r.w = fmaxf(fmaf(x.w, sc.w, sh.w), 0.f);
    return r;
}
__device__ __forceinline__ void acc4(float4& a, float4 x) {
    a.x += x.x; a.y += x.y; a.z += x.z; a.w += x.w;
}

template <bool BN>
__global__ __launch_bounds__(192) void gather_kernel(const float* __restrict__ H,
                                                     const int* __restrict__ rp,
                                                     const int* __restrict__ cols,
                                                     const float* __restrict__ scale,
                                                     const float* __restrict__ shift,
                                                     float* __restrict__ out) {
    int idx = blockIdx.x * 192 + threadIdx.x;
    int v = idx / 24, q = idx % 24;
    if (v >= N_NODES) return;

    float4 sc, sh;
    if (BN) {
        sc = ((const float4*)scale)[q];
        sh = ((const float4*)shift)[q];
    }
    const float4* Hq = (const float4*)H;  // row stride = 24 float4

    float4 self = Hq[(size_t)v * 24 + q];
    float4 acc = BN ? bn_relu4(self, sc, sh) : self;

    int beg = rp[v], end = rp[v + 1];
    int j = beg;
    for (; j + 3 < end; j += 4) {
        int u0 = cols[j], u1 = cols[j + 1], u2 = cols[j + 2], u3 = cols[j + 3];
        float4 x0 = Hq[(size_t)u0 * 24 + q];
        float4 x1 = Hq[(size_t)u1 * 24 + q];
        float4 x2 = Hq[(size_t)u2 * 24 + q];
        float4 x3 = Hq[(size_t)u3 * 24 + q];
        acc4(acc, BN ? bn_relu4(x0, sc, sh) : x0);
        acc4(acc, BN ? bn_relu4(x1, sc, sh) : x1);
        acc4(acc, BN ? bn_relu4(x2, sc, sh) : x2);
        acc4(acc, BN ? bn_relu4(x3, sc, sh) : x3);
    }
    for (; j < end; ++j) {
        int u = cols[j];
        float4 x = Hq[(size_t)u * 24 + q];
        acc4(acc, BN ? bn_relu4(x, sc, sh) : x);
    }
    ((float4*)out)[(size_t)v * 24 + q] = acc;
}

// ---------------------------------------------------------------------------
// BN stats, deterministic: register accumulate, LDS reduce, per-block
// partials; bn_finalize reduces partials and folds scale/shift.
// ---------------------------------------------------------------------------
__global__ __launch_bounds__(192) void bn_stats(const float4* __restrict__ Z4,
                                                float* __restrict__ psums,
                                                float* __restrict__ psq) {
    int q = threadIdx.x % 24, rs = threadIdx.x / 24;
    float4 s = make_float4(0.f, 0.f, 0.f, 0.f);
    float4 sq = make_float4(0.f, 0.f, 0.f, 0.f);
    for (int r = blockIdx.x * 8 + rs; r < N_NODES; r += gridDim.x * 8) {
        float4 v = Z4[(size_t)r * 24 + q];
        s.x += v.x; s.y += v.y; s.z += v.z; s.w += v.w;
        sq.x = fmaf(v.x, v.x, sq.x);
        sq.y = fmaf(v.y, v.y, sq.y);
        sq.z = fmaf(v.z, v.z, sq.z);
        sq.w = fmaf(v.w, v.w, sq.w);
    }
    __shared__ float4 ls[8][24], lq[8][24];
    ls[rs][q] = s;
    lq[rs][q] = sq;
    __syncthreads();
    if (threadIdx.x < 24) {
        float4 S = ls[0][q], Q = lq[0][q];
#pragma unroll
        for (int i = 1; i < 8; ++i) {
            acc4(S, ls[i][q]);
            acc4(Q, lq[i][q]);
        }
        ((float4*)(psums + (size_t)blockIdx.x * HID))[q] = S;
        ((float4*)(psq + (size_t)blockIdx.x * HID))[q] = Q;
    }
}

__global__ void bn_finalize(const float* __restrict__ psums, const float* __restrict__ psq,
                            const float* __restrict__ g, const float* __restrict__ be,
                            float* __restrict__ scale, float* __restrict__ shift) {
    int c = threadIdx.x;
    if (c < HID) {
        float S = 0.f, Q = 0.f;
        for (int b = 0; b < NB_STATS; ++b) {
            S += psums[(size_t)b * HID + c];
            Q += psq[(size_t)b * HID + c];
        }
        float mu = S * (1.0f / N_NODES);
        float var = Q * (1.0f / N_NODES) - mu * mu;
        float rstd = rsqrtf(var + 1e-5f);
        float sc = g[c] * rstd;
        scale[c] = sc;
        shift[c] = be[c] - mu * sc;
    }
}

// ---------------------------------------------------------------------------
// Readout: stage 16 BN+ReLU'd rows in LDS (coalesced), 16 lanes per row,
// shuffle-reduce log_softmax, coalesced store.
// ---------------------------------------------------------------------------
__global__ __launch_bounds__(256) void readout_kernel(const float* __restrict__ X,
                                                      const float* __restrict__ scale,
                                                      const float* __restrict__ shift,
                                                      const float* __restrict__ Wr,
                                                      const float* __restrict__ br,
                                                      float* __restrict__ out) {
    __shared__ float Ws[HID * NCLS];
    __shared__ float XL[16 * 97];
    __shared__ float scs[HID], shs[HID], bs[NCLS];
    for (int i = threadIdx.x; i < HID * NCLS / 4; i += 256)
        ((float4*)Ws)[i] = ((const float4*)Wr)[i];
    if (threadIdx.x < HID) {
        scs[threadIdx.x] = scale[threadIdx.x];
        shs[threadIdx.x] = shift[threadIdx.x];
    }
    if (threadIdx.x < NCLS) bs[threadIdx.x] = br[threadIdx.x];

    int rr = threadIdx.x >> 4, t = threadIdx.x & 15;
    for (int tile = blockIdx.x; tile < N_NODES / 16; tile += gridDim.x) {
        int rbase = tile * 16;
        __syncthreads();
        for (int i = threadIdx.x; i < 16 * HID; i += 256) {
            int row = i / HID, col = i - row * HID;
            float z = fmaf(X[(size_t)rbase * HID + i], scs[col], shs[col]);
            XL[row * 97 + col] = fmaxf(z, 0.f);
        }
        __syncthreads();
        float acc = bs[t];
        const float* xrow = &XL[rr * 97];
#pragma unroll 4
        for (int k = 0; k < HID; ++k) acc = fmaf(xrow[k], Ws[k * NCLS + t], acc);
        float m = acc;
#pragma unroll
        for (int off = 8; off; off >>= 1) m = fmaxf(m, __shfl_xor(m, off, 16));
        float e = expf(acc - m);
        float s = e;
#pragma unroll
        for (int off = 8; off; off >>= 1) s += __shfl_xor(s, off, 16);
        float lse = m + logf(s);
        out[(size_t)rbase * NCLS + threadIdx.x] = acc - lse;
    }
}

// ---------------------------------------------------------------------------
extern "C" void kernel_launch(void* const* d_in, const int* in_sizes, int n_in,
                              void* d_out, int out_size, void* d_ws, size_t ws_size,
                              hipStream_t stream) {
    const float* h     = (const float*)d_in[0];
    const int*   src   = (const int*)d_in[1];
    const int*   dst   = (const int*)d_in[2];
    const float* W_emb = (const float*)d_in[3];
    const float* b_emb = (const float*)d_in[4];
    const float* W1    = (const float*)d_in[5];
    const float* b1    = (const float*)d_in[6];
    const float* g1    = (const float*)d_in[7];
    const float* be1   = (const float*)d_in[8];
    const float* W2    = (const float*)d_in[9];
    const float* b2    = (const float*)d_in[10];
    const float* g2    = (const float*)d_in[11];
    const float* be2   = (const float*)d_in[12];
    const float* Wr    = (const float*)d_in[13];
    const float* br    = (const float*)d_in[14];

    const size_t nh = (size_t)N_NODES * HID;
    float* P0 = (float*)d_ws;          // 38.4 MB
    float* P1 = P0 + nh;               // 38.4 MB
    int* deg    = (int*)(P1 + nh);     // N
    int* rp     = deg + N_NODES;       // N+1
    int* cursor = rp + N_NODES + 1;    // N
    int* cols   = cursor + N_NODES;    // E
    int* bsums  = cols + N_EDGES;      // NB_SCAN
    int* boffs  = bsums + 512;         // NB_SCAN
    float* psums = (float*)(boffs + 512);   // NB_STATS*96
    float* psq   = psums + NB_STATS * HID;  // NB_STATS*96
    float* scale = psq + NB_STATS * HID;    // 96
    float* shift = scale + HID;             // 96

    const int blkA = (N_NODES * 24 + 191) / 192;     // 12500
    const int blkT = (N_NODES + 127) / 128;          // 782
    const int blkPart = 1024;

    // --- CSR build (XCD-partitioned) ---
    hipMemsetAsync(deg, 0, N_NODES * sizeof(int), stream);
    hist_part<<<blkPart, 256, 0, stream>>>((const int4*)dst, deg);
    scan_blocksum<<<NB_SCAN, 256, 0, stream>>>(deg, bsums);
    scan_offsets<<<1, 512, 0, stream>>>(bsums, boffs);
    scan_final<<<NB_SCAN, 256, 0, stream>>>(deg, boffs, rp, cursor);
    scatter_part<<<blkPart, 256, 0, stream>>>((const int4*)src, (const int4*)dst,
                                              cursor, cols);

    // --- embedding: P0 = h @ W_emb + b_emb ---
    hipLaunchKernelGGL((gemm_tile<IN_DIM>), dim3(blkT), dim3(192), 0, stream,
                       h, W_emb, b_emb, P0);

    // --- GIN layer 1 ---
    hipLaunchKernelGGL((gather_kernel<false>), dim3(blkA), dim3(192), 0, stream,
                       P0, rp, cols, nullptr, nullptr, P1);
    hipLaunchKernelGGL((gemm_tile<HID>), dim3(blkT), dim3(192), 0, stream,
                       P1, W1, b1, P0);                      // P0 = C1
    bn_stats<<<NB_STATS, 192, 0, stream>>>((const float4*)P0, psums, psq);
    bn_finalize<<<1, 128, 0, stream>>>(psums, psq, g1, be1, scale, shift);

    // --- GIN layer 2 (BN1+ReLU fused into gather) ---
    hipLaunchKernelGGL((gather_kernel<true>), dim3(blkA), dim3(192), 0, stream,
                       P0, rp, cols, scale, shift, P1);
    hipLaunchKernelGGL((gemm_tile<HID>), dim3(blkT), dim3(192), 0, stream,
                       P1, W2, b2, P0);                      // P0 = C2
    bn_stats<<<NB_STATS, 192, 0, stream>>>((const float4*)P0, psums, psq);
    bn_finalize<<<1, 128, 0, stream>>>(psums, psq, g2, be2, scale, shift);

    // --- readout (BN2+ReLU fused) + log_softmax ---
    readout_kernel<<<2048, 256, 0, stream>>>(P0, scale, shift, Wr, br, (float*)d_out);
}

// Round 6
// 482.302 us; speedup vs baseline: 1.6377x; 1.1465x over previous
//
#include <hip/hip_runtime.h>
#include <cmath>

#define N_NODES 100000
#define N_EDGES 1600000
#define IN_DIM 128
#define HID 96
#define NCLS 16
#define NB_SCAN 391   // ceil(N_NODES/256)
#define NPART 8
#define PART_SZ (N_NODES / NPART)  // 12500
#define NB_GATH 2048               // gather grid (fixed, for stats partials)

typedef unsigned int uint;
typedef unsigned short ushort;

__device__ __forceinline__ ushort f2bf(float x) {  // RNE f32->bf16
    uint b = __float_as_uint(x);
    uint r = (b + 0x7FFFu + ((b >> 16) & 1u)) >> 16;
    return (ushort)r;
}
__device__ __forceinline__ float bf2f(ushort u) {
    return __uint_as_float(((uint)u) << 16);
}
__device__ __forceinline__ float4 bn_relu4(float4 x, float4 sc, float4 sh) {
    float4 r;
    r.x = fmaxf(fmaf(x.x, sc.x, sh.x), 0.f);
    r.y = fmaxf(fmaf(x.y, sc.y, sh.y), 0.f);
    r.z = fmaxf(fmaf(x.z, sc.z, sh.z), 0.f);
    r.w = fmaxf(fmaf(x.w, sc.w, sh.w), 0.f);
    return r;
}
__device__ __forceinline__ void acc4(float4& a, float4 x) {
    a.x += x.x; a.y += x.y; a.z += x.z; a.w += x.w;
}

// ---------------------------------------------------------------------------
// wfuse: Wf[128][96] = W_emb @ W1 ; bf[96] = b_emb @ W1
// ---------------------------------------------------------------------------
__global__ __launch_bounds__(256) void wfuse(const float* __restrict__ W_emb,
                                             const float* __restrict__ W1,
                                             const float* __restrict__ b_emb,
                                             float* __restrict__ Wf,
                                             float* __restrict__ bf) {
    __shared__ float W1s[HID * HID];
    for (int i = threadIdx.x; i < HID * HID / 4; i += 256)
        ((float4*)W1s)[i] = ((const float4*)W1)[i];
    __syncthreads();
    int idx = blockIdx.x * 256 + threadIdx.x;
    if (idx < IN_DIM * HID) {
        int i = idx / HID, j = idx - (idx / HID) * HID;
        float acc = 0.f;
        for (int k = 0; k < HID; ++k)
            acc = fmaf(W_emb[(size_t)i * HID + k], W1s[k * HID + j], acc);
        Wf[idx] = acc;
    }
    if (idx < HID) {
        float acc = 0.f;
        for (int k = 0; k < HID; ++k)
            acc = fmaf(b_emb[k], W1s[k * HID + idx], acc);
        bf[idx] = acc;
    }
}

// ---------------------------------------------------------------------------
// Tiled GEMM -> bf16 table. Block = 192 thr = 32 row-clusters x 6 col-groups;
// thread = 4 rows x 16 cols. W group-major in LDS, stride K*16+4 (conflict-
// free). BNIN: apply relu(x*scale+shift) to input on the fly (prev layer BN).
// bias==nullptr -> zero init (bias added later in gather epilogue).
// ---------------------------------------------------------------------------
template <int K, bool BNIN>
__global__ __launch_bounds__(192) void gemm_bf16(const float* __restrict__ X,
                                                 const float* __restrict__ W,
                                                 const float* __restrict__ bias,
                                                 const float* __restrict__ scale,
                                                 const float* __restrict__ shift,
                                                 ushort* __restrict__ outB) {
    constexpr int GSTRIDE = K * 16 + 4;
    __shared__ float Ws[6 * GSTRIDE];
    __shared__ float bs[HID];
    __shared__ float scs[HID], shs[HID];
    for (int i = threadIdx.x; i < K * HID / 4; i += 192) {
        int flat = i * 4;
        int k = flat / HID, c = flat - k * HID;
        int g = c / 16, j = c - g * 16;
        *(float4*)&Ws[g * GSTRIDE + k * 16 + j] = ((const float4*)W)[i];
    }
    if (threadIdx.x < HID) {
        bs[threadIdx.x] = bias ? bias[threadIdx.x] : 0.f;
        if (BNIN) {
            scs[threadIdx.x] = scale[threadIdx.x];
            shs[threadIdx.x] = shift[threadIdx.x];
        }
    }
    __syncthreads();

    const int g = threadIdx.x % 6;
    const int rc = threadIdx.x / 6;
    const int rbase = blockIdx.x * 128 + rc * 4;
    const int r0 = min(rbase + 0, N_NODES - 1);
    const int r1 = min(rbase + 1, N_NODES - 1);
    const int r2 = min(rbase + 2, N_NODES - 1);
    const int r3 = min(rbase + 3, N_NODES - 1);
    const float* x0 = X + (size_t)r0 * K;
    const float* x1 = X + (size_t)r1 * K;
    const float* x2 = X + (size_t)r2 * K;
    const float* x3 = X + (size_t)r3 * K;
    const float* wg = Ws + g * GSTRIDE;

    float acc[4][16];
#pragma unroll
    for (int j = 0; j < 16; ++j) {
        float bj = bs[g * 16 + j];
        acc[0][j] = bj; acc[1][j] = bj; acc[2][j] = bj; acc[3][j] = bj;
    }

    for (int k = 0; k < K; k += 4) {
        float4 a0 = *(const float4*)(x0 + k);
        float4 a1 = *(const float4*)(x1 + k);
        float4 a2 = *(const float4*)(x2 + k);
        float4 a3 = *(const float4*)(x3 + k);
        if (BNIN) {
            float4 sc4 = *(const float4*)(scs + k);  // same addr all lanes: broadcast
            float4 sh4 = *(const float4*)(shs + k);
            a0 = bn_relu4(a0, sc4, sh4);
            a1 = bn_relu4(a1, sc4, sh4);
            a2 = bn_relu4(a2, sc4, sh4);
            a3 = bn_relu4(a3, sc4, sh4);
        }
#pragma unroll
        for (int kk = 0; kk < 4; ++kk) {
            const float* wrow = wg + (k + kk) * 16;
            float4 w0 = *(const float4*)(wrow + 0);
            float4 w1 = *(const float4*)(wrow + 4);
            float4 w2 = *(const float4*)(wrow + 8);
            float4 w3 = *(const float4*)(wrow + 12);
            float xs0 = kk == 0 ? a0.x : kk == 1 ? a0.y : kk == 2 ? a0.z : a0.w;
            float xs1 = kk == 0 ? a1.x : kk == 1 ? a1.y : kk == 2 ? a1.z : a1.w;
            float xs2 = kk == 0 ? a2.x : kk == 1 ? a2.y : kk == 2 ? a2.z : a2.w;
            float xs3 = kk == 0 ? a3.x : kk == 1 ? a3.y : kk == 2 ? a3.z : a3.w;
            const float wv[16] = {w0.x, w0.y, w0.z, w0.w, w1.x, w1.y, w1.z, w1.w,
                                  w2.x, w2.y, w2.z, w2.w, w3.x, w3.y, w3.z, w3.w};
#pragma unroll
            for (int j = 0; j < 16; ++j) {
                acc[0][j] = fmaf(xs0, wv[j], acc[0][j]);
                acc[1][j] = fmaf(xs1, wv[j], acc[1][j]);
                acc[2][j] = fmaf(xs2, wv[j], acc[2][j]);
                acc[3][j] = fmaf(xs3, wv[j], acc[3][j]);
            }
        }
    }
    const int rr[4] = {r0, r1, r2, r3};
    union PK { ushort u[8]; uint4 v; };
#pragma unroll
    for (int i = 0; i < 4; ++i) {
        ushort* orow = outB + (size_t)rr[i] * HID + g * 16;
        PK p0, p1;
#pragma unroll
        for (int j = 0; j < 8; ++j) {
            p0.u[j] = f2bf(acc[i][j]);
            p1.u[j] = f2bf(acc[i][j + 8]);
        }
        *(uint4*)(orow + 0) = p0.v;
        *(uint4*)(orow + 8) = p1.v;
    }
}

// ---------------------------------------------------------------------------
// CSR build, XCD-partitioned.
// ---------------------------------------------------------------------------
__global__ __launch_bounds__(256) void hist_part(const int4* __restrict__ dst4,
                                                 int* __restrict__ deg) {
    int pid = blockIdx.x & (NPART - 1);
    int slot = blockIdx.x >> 3, nslot = gridDim.x >> 3;
    int lo = pid * PART_SZ, hi = lo + PART_SZ;
    for (int i = slot * 256 + threadIdx.x; i < N_EDGES / 4; i += nslot * 256) {
        int4 d = dst4[i];
        if (d.x >= lo && d.x < hi) atomicAdd(&deg[d.x], 1);
        if (d.y >= lo && d.y < hi) atomicAdd(&deg[d.y], 1);
        if (d.z >= lo && d.z < hi) atomicAdd(&deg[d.z], 1);
        if (d.w >= lo && d.w < hi) atomicAdd(&deg[d.w], 1);
    }
}

__global__ __launch_bounds__(256) void scatter_part(const int4* __restrict__ src4,
                                                    const int4* __restrict__ dst4,
                                                    int* __restrict__ cursor,
                                                    int* __restrict__ cols) {
    int pid = blockIdx.x & (NPART - 1);
    int slot = blockIdx.x >> 3, nslot = gridDim.x >> 3;
    int lo = pid * PART_SZ, hi = lo + PART_SZ;
    for (int i = slot * 256 + threadIdx.x; i < N_EDGES / 4; i += nslot * 256) {
        int4 d = dst4[i];
        int4 s = src4[i];
        if (d.x >= lo && d.x < hi) cols[atomicAdd(&cursor[d.x], 1)] = s.x;
        if (d.y >= lo && d.y < hi) cols[atomicAdd(&cursor[d.y], 1)] = s.y;
        if (d.z >= lo && d.z < hi) cols[atomicAdd(&cursor[d.z], 1)] = s.z;
        if (d.w >= lo && d.w < hi) cols[atomicAdd(&cursor[d.w], 1)] = s.w;
    }
}

__global__ void scan_blocksum(const int* __restrict__ deg, int* __restrict__ bsums) {
    __shared__ int sm[256];
    int t = threadIdx.x;
    int i = blockIdx.x * 256 + t;
    sm[t] = (i < N_NODES) ? deg[i] : 0;
    __syncthreads();
    for (int s = 128; s > 0; s >>= 1) {
        if (t < s) sm[t] += sm[t + s];
        __syncthreads();
    }
    if (t == 0) bsums[blockIdx.x] = sm[0];
}

__global__ void scan_offsets(const int* __restrict__ bsums, int* __restrict__ boffs) {
    __shared__ int tmp[512];
    int t = threadIdx.x;
    int v = (t < NB_SCAN) ? bsums[t] : 0;
    tmp[t] = v;
    __syncthreads();
    for (int off = 1; off < 512; off <<= 1) {
        int a = (t >= off) ? tmp[t - off] : 0;
        __syncthreads();
        tmp[t] += a;
        __syncthreads();
    }
    if (t < NB_SCAN) boffs[t] = tmp[t] - v;  // exclusive
}

__global__ void scan_final(const int* __restrict__ deg, const int* __restrict__ boffs,
                           int* __restrict__ rp, int* __restrict__ cursor) {
    __shared__ int tmp[256];
    int t = threadIdx.x;
    int i = blockIdx.x * 256 + t;
    int val = (i < N_NODES) ? deg[i] : 0;
    tmp[t] = val;
    __syncthreads();
    for (int off = 1; off < 256; off <<= 1) {
        int a = (t >= off) ? tmp[t - off] : 0;
        __syncthreads();
        tmp[t] += a;
        __syncthreads();
    }
    int excl = tmp[t] - val + boffs[blockIdx.x];
    if (i < N_NODES) {
        rp[i] = excl;
        cursor[i] = excl;
        if (i == N_NODES - 1) rp[N_NODES] = excl + val;
    }
}

// ---------------------------------------------------------------------------
// Gather + fused BN stats: z[v] = bias + T[v] + sum_u T[u]  (T bf16),
// accumulate per-column sum/sumsq in registers, LDS reduce, per-block
// partials (deterministic). 192 thr = 8 node-slots x 24 float4-chunks;
// grid-stride over nodes with NB_GATH blocks.
// ---------------------------------------------------------------------------
__device__ __forceinline__ float4 ld_bf4(const ushort* __restrict__ T, int u, int q) {
    ushort4 w = *(const ushort4*)(T + (size_t)u * HID + q * 4);
    float4 r;
    r.x = bf2f(w.x); r.y = bf2f(w.y); r.z = bf2f(w.z); r.w = bf2f(w.w);
    return r;
}

__global__ __launch_bounds__(192) void gather_stats(const ushort* __restrict__ T,
                                                    const int* __restrict__ rp,
                                                    const int* __restrict__ cols,
                                                    const float* __restrict__ bias,
                                                    float* __restrict__ z,
                                                    float* __restrict__ psums,
                                                    float* __restrict__ psq) {
    const int q = threadIdx.x % 24, rs = threadIdx.x / 24;
    const float4 bias4 = ((const float4*)bias)[q];
    float4 s = make_float4(0.f, 0.f, 0.f, 0.f);
    float4 sq = make_float4(0.f, 0.f, 0.f, 0.f);

    for (int v = blockIdx.x * 8 + rs; v < N_NODES; v += NB_GATH * 8) {
        float4 acc = bias4;
        acc4(acc, ld_bf4(T, v, q));
        int beg = rp[v], end = rp[v + 1];
        int j = beg;
        for (; j + 3 < end; j += 4) {
            int u0 = cols[j], u1 = cols[j + 1], u2 = cols[j + 2], u3 = cols[j + 3];
            acc4(acc, ld_bf4(T, u0, q));
            acc4(acc, ld_bf4(T, u1, q));
            acc4(acc, ld_bf4(T, u2, q));
            acc4(acc, ld_bf4(T, u3, q));
        }
        for (; j < end; ++j) acc4(acc, ld_bf4(T, cols[j], q));
        ((float4*)z)[(size_t)v * 24 + q] = acc;
        s.x += acc.x; s.y += acc.y; s.z += acc.z; s.w += acc.w;
        sq.x = fmaf(acc.x, acc.x, sq.x);
        sq.y = fmaf(acc.y, acc.y, sq.y);
        sq.z = fmaf(acc.z, acc.z, sq.z);
        sq.w = fmaf(acc.w, acc.w, sq.w);
    }

    __shared__ float4 ls[8][24], lq[8][24];
    ls[rs][q] = s;
    lq[rs][q] = sq;
    __syncthreads();
    if (threadIdx.x < 24) {
        float4 S = ls[0][threadIdx.x], Q = lq[0][threadIdx.x];
#pragma unroll
        for (int i = 1; i < 8; ++i) {
            acc4(S, ls[i][threadIdx.x]);
            acc4(Q, lq[i][threadIdx.x]);
        }
        ((float4*)(psums + (size_t)blockIdx.x * HID))[threadIdx.x] = S;
        ((float4*)(psq + (size_t)blockIdx.x * HID))[threadIdx.x] = Q;
    }
}

// ---------------------------------------------------------------------------
// Reduce NB_GATH partials -> folded scale/shift. 384 thr = 96 cols x 4 slices.
// ---------------------------------------------------------------------------
__global__ __launch_bounds__(384) void bn_finalize(const float* __restrict__ psums,
                                                   const float* __restrict__ psq,
                                                   const float* __restrict__ g,
                                                   const float* __restrict__ be,
                                                   float* __restrict__ scale,
                                                   float* __restrict__ shift) {
    int c = threadIdx.x % 96, h = threadIdx.x / 96;
    float S = 0.f, Q = 0.f;
    for (int b = h * (NB_GATH / 4); b < (h + 1) * (NB_GATH / 4); ++b) {
        S += psums[(size_t)b * HID + c];
        Q += psq[(size_t)b * HID + c];
    }
    __shared__ float lS[4][96], lQ[4][96];
    lS[h][c] = S;
    lQ[h][c] = Q;
    __syncthreads();
    if (threadIdx.x < 96) {
        S = lS[0][c] + lS[1][c] + lS[2][c] + lS[3][c];
        Q = lQ[0][c] + lQ[1][c] + lQ[2][c] + lQ[3][c];
        float mu = S * (1.0f / N_NODES);
        float var = Q * (1.0f / N_NODES) - mu * mu;
        float rstd = rsqrtf(var + 1e-5f);
        float sc = g[c] * rstd;
        scale[c] = sc;
        shift[c] = be[c] - mu * sc;
    }
}

// ---------------------------------------------------------------------------
// Readout: BN2+ReLU fused on input, LDS-tiled, 16 lanes/row log_softmax.
// ---------------------------------------------------------------------------
__global__ __launch_bounds__(256) void readout_kernel(const float* __restrict__ X,
                                                      const float* __restrict__ scale,
                                                      const float* __restrict__ shift,
                                                      const float* __restrict__ Wr,
                                                      const float* __restrict__ br,
                                                      float* __restrict__ out) {
    __shared__ float Ws[HID * NCLS];
    __shared__ float XL[16 * 97];
    __shared__ float scs[HID], shs[HID], bs[NCLS];
    for (int i = threadIdx.x; i < HID * NCLS / 4; i += 256)
        ((float4*)Ws)[i] = ((const float4*)Wr)[i];
    if (threadIdx.x < HID) {
        scs[threadIdx.x] = scale[threadIdx.x];
        shs[threadIdx.x] = shift[threadIdx.x];
    }
    if (threadIdx.x < NCLS) bs[threadIdx.x] = br[threadIdx.x];

    int rr = threadIdx.x >> 4, t = threadIdx.x & 15;
    for (int tile = blockIdx.x; tile < N_NODES / 16; tile += gridDim.x) {
        int rbase = tile * 16;
        __syncthreads();
        for (int i = threadIdx.x; i < 16 * HID; i += 256) {
            int row = i / HID, col = i - row * HID;
            float z = fmaf(X[(size_t)rbase * HID + i], scs[col], shs[col]);
            XL[row * 97 + col] = fmaxf(z, 0.f);
        }
        __syncthreads();
        float acc = bs[t];
        const float* xrow = &XL[rr * 97];
#pragma unroll 4
        for (int k = 0; k < HID; ++k) acc = fmaf(xrow[k], Ws[k * NCLS + t], acc);
        float m = acc;
#pragma unroll
        for (int off = 8; off; off >>= 1) m = fmaxf(m, __shfl_xor(m, off, 16));
        float e = expf(acc - m);
        float s = e;
#pragma unroll
        for (int off = 8; off; off >>= 1) s += __shfl_xor(s, off, 16);
        float lse = m + logf(s);
        out[(size_t)rbase * NCLS + threadIdx.x] = acc - lse;
    }
}

// ---------------------------------------------------------------------------
extern "C" void kernel_launch(void* const* d_in, const int* in_sizes, int n_in,
                              void* d_out, int out_size, void* d_ws, size_t ws_size,
                              hipStream_t stream) {
    const float* h     = (const float*)d_in[0];
    const int*   src   = (const int*)d_in[1];
    const int*   dst   = (const int*)d_in[2];
    const float* W_emb = (const float*)d_in[3];
    const float* b_emb = (const float*)d_in[4];
    const float* W1    = (const float*)d_in[5];
    const float* b1    = (const float*)d_in[6];
    const float* g1    = (const float*)d_in[7];
    const float* be1   = (const float*)d_in[8];
    const float* W2    = (const float*)d_in[9];
    const float* b2    = (const float*)d_in[10];
    const float* g2    = (const float*)d_in[11];
    const float* be2   = (const float*)d_in[12];
    const float* Wr    = (const float*)d_in[13];
    const float* br    = (const float*)d_in[14];

    const size_t nh = (size_t)N_NODES * HID;
    float*  z    = (float*)d_ws;              // 38.4 MB (z1, then z2)
    ushort* T    = (ushort*)(z + nh);         // 19.2 MB bf16 table (T1, then T2)
    int* deg     = (int*)(T + nh);            // N
    int* rp      = deg + N_NODES;             // N+1
    int* cursor  = rp + N_NODES + 1;          // N
    int* cols    = cursor + N_NODES;          // E
    int* bsums   = cols + N_EDGES;            // 512
    int* boffs   = bsums + 512;               // 512
    float* psums = (float*)(boffs + 512);     // NB_GATH*96
    float* psq   = psums + (size_t)NB_GATH * HID;
    float* scale = psq + (size_t)NB_GATH * HID;   // 96
    float* shift = scale + HID;                    // 96
    float* Wf    = shift + HID;                    // 128*96
    float* bf    = Wf + IN_DIM * HID;              // 96

    const int blkT = (N_NODES + 127) / 128;   // 782
    const int blkPart = 1024;

    // --- CSR build (XCD-partitioned) + fused weight precompute ---
    hipMemsetAsync(deg, 0, N_NODES * sizeof(int), stream);
    hist_part<<<blkPart, 256, 0, stream>>>((const int4*)dst, deg);
    scan_blocksum<<<NB_SCAN, 256, 0, stream>>>(deg, bsums);
    scan_offsets<<<1, 512, 0, stream>>>(bsums, boffs);
    scan_final<<<NB_SCAN, 256, 0, stream>>>(deg, boffs, rp, cursor);
    scatter_part<<<blkPart, 256, 0, stream>>>((const int4*)src, (const int4*)dst,
                                              cursor, cols);
    wfuse<<<(IN_DIM * HID + 255) / 256, 256, 0, stream>>>(W_emb, W1, b_emb, Wf, bf);

    // --- layer 1: T1 = h @ Wf + bf (bf16);  z1 = gather(T1) + b1 (+stats) ---
    hipLaunchKernelGGL((gemm_bf16<IN_DIM, false>), dim3(blkT), dim3(192), 0, stream,
                       h, Wf, bf, nullptr, nullptr, T);
    gather_stats<<<NB_GATH, 192, 0, stream>>>(T, rp, cols, b1, z, psums, psq);
    bn_finalize<<<1, 384, 0, stream>>>(psums, psq, g1, be1, scale, shift);

    // --- layer 2: T2 = bn_relu(z1) @ W2 (bf16);  z2 = gather(T2) + b2 ---
    hipLaunchKernelGGL((gemm_bf16<HID, true>), dim3(blkT), dim3(192), 0, stream,
                       z, W2, nullptr, scale, shift, T);
    gather_stats<<<NB_GATH, 192, 0, stream>>>(T, rp, cols, b2, z, psums, psq);
    bn_finalize<<<1, 384, 0, stream>>>(psums, psq, g2, be2, scale, shift);

    // --- readout (BN2+ReLU fused) + log_softmax ---
    readout_kernel<<<2048, 256, 0, stream>>>(z, scale, shift, Wr, br, (float*)d_out);
}